// Round 1
// baseline (1931.924 us; speedup 1.0000x reference)
//
#include <hip/hip_runtime.h>
#include <math.h>

// ---------------- float <-> monotonic uint key (for atomicMax on floats) ----
__device__ __forceinline__ unsigned fkey(float f) {
    unsigned u = __float_as_uint(f);
    return (u & 0x80000000u) ? ~u : (u | 0x80000000u);
}
__device__ __forceinline__ float funkey(unsigned u) {
    return (u & 0x80000000u) ? __uint_as_float(u & 0x7FFFFFFFu)
                             : __uint_as_float(~u);
}

// ---------------- GEMM (h = X @ W) fused with alpha_src/alpha_dst -----------
// X:[n,128] W:[128,128] -> Hout:[n,128]; AS/AD:[n,H] where
// AS[n][h] = sum_c Hout[n][h*C+c] * a_src[h*C+c]   (C = 128/H)
template <int H>
__global__ void gemm_alpha(const float* __restrict__ X, const float* __restrict__ W,
                           const float* __restrict__ a_src, const float* __restrict__ a_dst,
                           float* __restrict__ Hout, float* __restrict__ AS,
                           float* __restrict__ AD, int n) {
    constexpr int C = 128 / H;
    constexpr int NPB = 8;  // nodes per block
    __shared__ float xs[NPB][128];
    __shared__ float red[2][NPB][2];
    const int j = threadIdx.x;  // 0..127 (output column)
    const int n0 = blockIdx.x * NPB;

    #pragma unroll
    for (int r = 0; r < NPB; ++r) {
        int nn = n0 + r;
        xs[r][j] = (nn < n) ? X[nn * 128 + j] : 0.f;
    }
    __syncthreads();

    float acc[NPB];
    #pragma unroll
    for (int r = 0; r < NPB; ++r) acc[r] = 0.f;

    for (int k = 0; k < 128; ++k) {
        float w = W[k * 128 + j];
        #pragma unroll
        for (int r = 0; r < NPB; ++r) acc[r] += xs[r][k] * w;
    }

    const float asj = a_src[j];
    const float adj = a_dst[j];
    const int wid = j >> 6;
    const int lane = j & 63;

    #pragma unroll
    for (int r = 0; r < NPB; ++r) {
        const int nn = n0 + r;
        float vs = acc[r] * asj;
        float vd = acc[r] * adj;
        // reduce within groups of min(C,64) lanes
        #pragma unroll
        for (int off = (C > 64 ? 32 : C / 2); off >= 1; off >>= 1) {
            vs += __shfl_xor(vs, off);
            vd += __shfl_xor(vd, off);
        }
        if (C == 128) {
            if (lane == 0) { red[wid][r][0] = vs; red[wid][r][1] = vd; }
        } else {
            if (nn < n && (j & (C - 1)) == 0) {
                int h = j / C;
                AS[nn * H + h] = vs;
                AD[nn * H + h] = vd;
            }
        }
        if (nn < n) Hout[nn * 128 + j] = acc[r];
    }
    if (C == 128) {
        __syncthreads();
        if (j < NPB) {
            int nn = n0 + j;
            if (nn < n) {
                AS[nn] = red[0][j][0] + red[1][j][0];
                AD[nn] = red[0][j][1] + red[1][j][1];
            }
        }
    }
}

// ---------------- edge kernels ----------------------------------------------
// edge id e in [0, E+n): e<E -> (src=ei[e], dst=ei[E+e]); else self loop.
template <int H>
__global__ void edge_max(const int* __restrict__ ei, const float* __restrict__ AS,
                         const float* __restrict__ AD, unsigned* __restrict__ M,
                         int E, int etot) {
    int e = blockIdx.x * blockDim.x + threadIdx.x;
    if (e >= etot) return;
    int s, d;
    if (e < E) { s = ei[e]; d = ei[E + e]; } else { s = d = e - E; }
    #pragma unroll
    for (int h = 0; h < H; ++h) {
        float x = AS[s * H + h] + AD[d * H + h];
        float lr = x > 0.f ? x : 0.2f * x;
        atomicMax(&M[d * H + h], fkey(lr));
    }
}

template <int H>
__global__ void edge_den(const int* __restrict__ ei, const float* __restrict__ AS,
                         const float* __restrict__ AD, const unsigned* __restrict__ M,
                         float* __restrict__ DEN, int E, int etot) {
    int e = blockIdx.x * blockDim.x + threadIdx.x;
    if (e >= etot) return;
    int s, d;
    if (e < E) { s = ei[e]; d = ei[E + e]; } else { s = d = e - E; }
    #pragma unroll
    for (int h = 0; h < H; ++h) {
        float x = AS[s * H + h] + AD[d * H + h];
        float lr = x > 0.f ? x : 0.2f * x;
        float m = funkey(M[d * H + h]);
        atomicAdd(&DEN[d * H + h], expf(lr - m));
    }
}

// one wave (64 lanes) per edge; lane handles channels 2l, 2l+1
template <int H>
__global__ void edge_agg(const int* __restrict__ ei, const float* __restrict__ AS,
                         const float* __restrict__ AD, const unsigned* __restrict__ M,
                         const float* __restrict__ DEN, const float* __restrict__ Hin,
                         float* __restrict__ OUT, int E, int etot) {
    constexpr int C = 128 / H;
    long long tid = (long long)blockIdx.x * blockDim.x + threadIdx.x;
    int e = (int)(tid >> 6);
    int lane = (int)(tid & 63);
    if (e >= etot) return;
    int s, d;
    if (e < E) { s = ei[e]; d = ei[E + e]; } else { s = d = e - E; }
    int c0 = lane * 2;
    int h = c0 / C;
    float x = AS[s * H + h] + AD[d * H + h];
    float lr = x > 0.f ? x : 0.2f * x;
    float m = funkey(M[d * H + h]);
    float alpha = expf(lr - m) / DEN[d * H + h];
    const float2 v = *reinterpret_cast<const float2*>(Hin + (long long)s * 128 + c0);
    atomicAdd(&OUT[(long long)d * 128 + c0], v.x * alpha);
    atomicAdd(&OUT[(long long)d * 128 + c0 + 1], v.y * alpha);
}

// ---------------- finalize ---------------------------------------------------
__global__ void fin_elu(const float* __restrict__ AGG, const float* __restrict__ b,
                        float* __restrict__ OUT, int total) {
    int i = blockIdx.x * blockDim.x + threadIdx.x;
    if (i >= total) return;
    float v = AGG[i] + b[i & 127];
    OUT[i] = v > 0.f ? v : expm1f(v);
}
__global__ void fin_bias(float* __restrict__ OUT, const float* __restrict__ b, int total) {
    int i = blockIdx.x * blockDim.x + threadIdx.x;
    if (i >= total) return;
    OUT[i] += b[i & 127];
}

// ---------------- launch -----------------------------------------------------
extern "C" void kernel_launch(void* const* d_in, const int* in_sizes, int n_in,
                              void* d_out, int out_size, void* d_ws, size_t ws_size,
                              hipStream_t stream) {
    const float* x   = (const float*)d_in[0];
    const int*   ei  = (const int*)d_in[1];
    const float* W1  = (const float*)d_in[2];
    const float* as1 = (const float*)d_in[3];
    const float* ad1 = (const float*)d_in[4];
    const float* b1  = (const float*)d_in[5];
    const float* W2  = (const float*)d_in[6];
    const float* as2 = (const float*)d_in[7];
    const float* ad2 = (const float*)d_in[8];
    const float* b2  = (const float*)d_in[9];
    float* out = (float*)d_out;

    const int n = in_sizes[0] / 128;
    const int E = in_sizes[1] / 2;
    const int etot = E + n;

    char* p = (char*)d_ws;
    float* bufA = (float*)p; p += (size_t)n * 128 * 4;   // h1, then elu(out1)
    float* bufB = (float*)p; p += (size_t)n * 128 * 4;   // agg1, then h2
    float*    AS1 = (float*)p;    p += (size_t)n * 4 * 4;
    float*    AD1 = (float*)p;    p += (size_t)n * 4 * 4;
    unsigned* M1  = (unsigned*)p; p += (size_t)n * 4 * 4;
    float*    DEN1= (float*)p;    p += (size_t)n * 4 * 4;
    float*    AS2 = (float*)p;    p += (size_t)n * 4;
    float*    AD2 = (float*)p;    p += (size_t)n * 4;
    unsigned* M2  = (unsigned*)p; p += (size_t)n * 4;
    float*    DEN2= (float*)p;    p += (size_t)n * 4;

    // zero accumulators (fkey-space 0 acts as -inf for max; 0.f for sums)
    hipMemsetAsync(bufB, 0, (size_t)n * 128 * 4, stream);
    hipMemsetAsync(M1,   0, (size_t)n * 4 * 4, stream);
    hipMemsetAsync(DEN1, 0, (size_t)n * 4 * 4, stream);
    hipMemsetAsync(M2,   0, (size_t)n * 4, stream);
    hipMemsetAsync(DEN2, 0, (size_t)n * 4, stream);
    hipMemsetAsync(out,  0, (size_t)n * 128 * 4, stream);

    const int eb = 256;
    const int egrid = (etot + eb - 1) / eb;
    const int agrid = (int)(((long long)etot * 64 + eb - 1) / eb);
    const int fgrid = (n * 128 + eb - 1) / eb;
    const int ggrid = (n + 7) / 8;

    // ---- layer 1 (H=4, C=32, concat) ----
    gemm_alpha<4><<<ggrid, 128, 0, stream>>>(x, W1, as1, ad1, bufA, AS1, AD1, n);
    edge_max<4><<<egrid, eb, 0, stream>>>(ei, AS1, AD1, M1, E, etot);
    edge_den<4><<<egrid, eb, 0, stream>>>(ei, AS1, AD1, M1, DEN1, E, etot);
    edge_agg<4><<<agrid, eb, 0, stream>>>(ei, AS1, AD1, M1, DEN1, bufA, bufB, E, etot);
    fin_elu<<<fgrid, eb, 0, stream>>>(bufB, b1, bufA, n * 128);   // bufA = elu(agg+b1)

    // ---- layer 2 (H=1, C=128, mean over 1 head = identity) ----
    gemm_alpha<1><<<ggrid, 128, 0, stream>>>(bufA, W2, as2, ad2, bufB, AS2, AD2, n);
    edge_max<1><<<egrid, eb, 0, stream>>>(ei, AS2, AD2, M2, E, etot);
    edge_den<1><<<egrid, eb, 0, stream>>>(ei, AS2, AD2, M2, DEN2, E, etot);
    edge_agg<1><<<agrid, eb, 0, stream>>>(ei, AS2, AD2, M2, DEN2, bufB, out, E, etot);
    fin_bias<<<fgrid, eb, 0, stream>>>(out, b2, n * 128);
}

// Round 2
// 441.233 us; speedup vs baseline: 4.3785x; 4.3785x over previous
//
#include <hip/hip_runtime.h>
#include <math.h>

// ---------------- GEMM (h = X @ W) fused with alpha_src/alpha_dst -----------
template <int H>
__global__ void gemm_alpha(const float* __restrict__ X, const float* __restrict__ W,
                           const float* __restrict__ a_src, const float* __restrict__ a_dst,
                           float* __restrict__ Hout, float* __restrict__ AS,
                           float* __restrict__ AD, int n) {
    constexpr int C = 128 / H;
    constexpr int NPB = 8;  // nodes per block
    __shared__ float xs[NPB][128];
    __shared__ float red[2][NPB][2];
    const int j = threadIdx.x;  // 0..127 (output column)
    const int n0 = blockIdx.x * NPB;

    #pragma unroll
    for (int r = 0; r < NPB; ++r) {
        int nn = n0 + r;
        xs[r][j] = (nn < n) ? X[nn * 128 + j] : 0.f;
    }
    __syncthreads();

    float acc[NPB];
    #pragma unroll
    for (int r = 0; r < NPB; ++r) acc[r] = 0.f;

    for (int k = 0; k < 128; ++k) {
        float w = W[k * 128 + j];
        #pragma unroll
        for (int r = 0; r < NPB; ++r) acc[r] += xs[r][k] * w;
    }

    const float asj = a_src[j];
    const float adj = a_dst[j];
    const int wid = j >> 6;
    const int lane = j & 63;

    #pragma unroll
    for (int r = 0; r < NPB; ++r) {
        const int nn = n0 + r;
        float vs = acc[r] * asj;
        float vd = acc[r] * adj;
        #pragma unroll
        for (int off = (C > 64 ? 32 : C / 2); off >= 1; off >>= 1) {
            vs += __shfl_xor(vs, off);
            vd += __shfl_xor(vd, off);
        }
        if (C == 128) {
            if (lane == 0) { red[wid][r][0] = vs; red[wid][r][1] = vd; }
        } else {
            if (nn < n && (j & (C - 1)) == 0) {
                int h = j / C;
                AS[nn * H + h] = vs;
                AD[nn * H + h] = vd;
            }
        }
        if (nn < n) Hout[nn * 128 + j] = acc[r];
    }
    if (C == 128) {
        __syncthreads();
        if (j < NPB) {
            int nn = n0 + j;
            if (nn < n) {
                AS[nn] = red[0][j][0] + red[1][j][0];
                AD[nn] = red[0][j][1] + red[1][j][1];
            }
        }
    }
}

// ---------------- CSR build (counting sort by dst) ---------------------------
// edge id e in [0, E+n): e<E -> (src=ei[e], dst=ei[E+e]); else self loop e-E.
__global__ void hist_dst(const int* __restrict__ ei, int* __restrict__ counts,
                         int E, int etot) {
    int e = blockIdx.x * blockDim.x + threadIdx.x;
    if (e >= etot) return;
    int d = (e < E) ? ei[E + e] : e - E;
    atomicAdd(&counts[d], 1);
}

__global__ void scan1(const int* __restrict__ counts, int* __restrict__ offsets,
                      int* __restrict__ bsums, int n) {
    __shared__ int tmp[256];
    int tid = threadIdx.x;
    int i = blockIdx.x * 256 + tid;
    int v = (i < n) ? counts[i] : 0;
    tmp[tid] = v;
    __syncthreads();
    #pragma unroll
    for (int off = 1; off < 256; off <<= 1) {
        int t = (tid >= off) ? tmp[tid - off] : 0;
        __syncthreads();
        tmp[tid] += t;
        __syncthreads();
    }
    if (i < n) offsets[i] = tmp[tid] - v;  // exclusive within block
    if (tid == 255) bsums[blockIdx.x] = tmp[255];
}

__global__ void scan2(int* __restrict__ bsums, int nb) {
    __shared__ int tmp[256];
    int tid = threadIdx.x;
    int v = (tid < nb) ? bsums[tid] : 0;
    tmp[tid] = v;
    __syncthreads();
    #pragma unroll
    for (int off = 1; off < 256; off <<= 1) {
        int t = (tid >= off) ? tmp[tid - off] : 0;
        __syncthreads();
        tmp[tid] += t;
        __syncthreads();
    }
    if (tid < nb) bsums[tid] = tmp[tid] - v;  // exclusive
}

__global__ void scan3(int* __restrict__ offsets, const int* __restrict__ bsums,
                      int* __restrict__ cursor, int n, int etot) {
    int i = blockIdx.x * 256 + threadIdx.x;
    if (i < n) {
        int o = offsets[i] + bsums[blockIdx.x];
        offsets[i] = o;
        cursor[i] = o;
    }
    if (i == 0) offsets[n] = etot;
}

__global__ void csr_fill(const int* __restrict__ ei, int* __restrict__ cursor,
                         int* __restrict__ csr_src, int E, int etot) {
    int e = blockIdx.x * blockDim.x + threadIdx.x;
    if (e >= etot) return;
    int s, d;
    if (e < E) { s = ei[e]; d = ei[E + e]; } else { s = d = e - E; }
    int pos = atomicAdd(&cursor[d], 1);
    csr_src[pos] = s;
}

// ---------------- per-node softmax stats (m, den) -----------------------------
template <int H>
__global__ void node_mden(const int* __restrict__ offsets, const int* __restrict__ csr_src,
                          const float* __restrict__ AS, const float* __restrict__ AD,
                          float* __restrict__ M, float* __restrict__ DEN, int n) {
    const int wid = threadIdx.x >> 6;
    const int lane = threadIdx.x & 63;
    const int d = blockIdx.x * 4 + wid;
    if (d >= n) return;
    const int off = offsets[d];
    const int deg = offsets[d + 1] - off;

    float adv[H], mx[H], sm[H];
    #pragma unroll
    for (int h = 0; h < H; ++h) { adv[h] = AD[d * H + h]; mx[h] = -3.4e38f; sm[h] = 0.f; }

    for (int k = lane; k < deg; k += 64) {
        int s = csr_src[off + k];
        #pragma unroll
        for (int h = 0; h < H; ++h) {
            float x = AS[s * H + h] + adv[h];
            float lr = x > 0.f ? x : 0.2f * x;
            mx[h] = fmaxf(mx[h], lr);
        }
    }
    #pragma unroll
    for (int h = 0; h < H; ++h)
        #pragma unroll
        for (int o = 32; o >= 1; o >>= 1) mx[h] = fmaxf(mx[h], __shfl_xor(mx[h], o));

    for (int k = lane; k < deg; k += 64) {
        int s = csr_src[off + k];
        #pragma unroll
        for (int h = 0; h < H; ++h) {
            float x = AS[s * H + h] + adv[h];
            float lr = x > 0.f ? x : 0.2f * x;
            sm[h] += expf(lr - mx[h]);
        }
    }
    #pragma unroll
    for (int h = 0; h < H; ++h)
        #pragma unroll
        for (int o = 32; o >= 1; o >>= 1) sm[h] += __shfl_xor(sm[h], o);

    if (lane == 0) {
        #pragma unroll
        for (int h = 0; h < H; ++h) { M[d * H + h] = mx[h]; DEN[d * H + h] = sm[h]; }
    }
}

// ---------------- per-node gather aggregation (+ fused epilogue) --------------
// MODE 0: out = elu(agg + bias);  MODE 1: out = agg + bias
template <int H, int MODE>
__global__ void node_agg(const int* __restrict__ offsets, const int* __restrict__ csr_src,
                         const float* __restrict__ AS, const float* __restrict__ AD,
                         const float* __restrict__ M, const float* __restrict__ DEN,
                         const float* __restrict__ Hin, const float* __restrict__ bias,
                         float* __restrict__ OUT, int n) {
    constexpr int C = 128 / H;
    const int wid = threadIdx.x >> 6;
    const int lane = threadIdx.x & 63;
    const int d = blockIdx.x * 4 + wid;
    if (d >= n) return;
    const int off = offsets[d];
    const int deg = offsets[d + 1] - off;
    const int c0 = lane * 2;
    const int h = c0 / C;

    const float adv = AD[d * H + h];
    const float m = M[d * H + h];
    const float dinv = 1.f / DEN[d * H + h];

    float a0 = 0.f, a1 = 0.f;
    for (int k = 0; k < deg; ++k) {
        int s = csr_src[off + k];
        float x = AS[s * H + h] + adv;
        float lr = x > 0.f ? x : 0.2f * x;
        float alpha = expf(lr - m) * dinv;
        const float2 v = *reinterpret_cast<const float2*>(Hin + (size_t)s * 128 + c0);
        a0 += alpha * v.x;
        a1 += alpha * v.y;
    }
    float o0 = a0 + bias[c0];
    float o1 = a1 + bias[c0 + 1];
    if (MODE == 0) {
        o0 = o0 > 0.f ? o0 : expm1f(o0);
        o1 = o1 > 0.f ? o1 : expm1f(o1);
    }
    OUT[(size_t)d * 128 + c0] = o0;
    OUT[(size_t)d * 128 + c0 + 1] = o1;
}

// ---------------- launch -----------------------------------------------------
extern "C" void kernel_launch(void* const* d_in, const int* in_sizes, int n_in,
                              void* d_out, int out_size, void* d_ws, size_t ws_size,
                              hipStream_t stream) {
    const float* x   = (const float*)d_in[0];
    const int*   ei  = (const int*)d_in[1];
    const float* W1  = (const float*)d_in[2];
    const float* as1 = (const float*)d_in[3];
    const float* ad1 = (const float*)d_in[4];
    const float* b1  = (const float*)d_in[5];
    const float* W2  = (const float*)d_in[6];
    const float* as2 = (const float*)d_in[7];
    const float* ad2 = (const float*)d_in[8];
    const float* b2  = (const float*)d_in[9];
    float* out = (float*)d_out;

    const int n = in_sizes[0] / 128;
    const int E = in_sizes[1] / 2;
    const int etot = E + n;

    char* p = (char*)d_ws;
    float* bufA = (float*)p; p += (size_t)n * 128 * 4;
    float* bufB = (float*)p; p += (size_t)n * 128 * 4;
    float* AS   = (float*)p; p += (size_t)n * 4 * 4;
    float* AD   = (float*)p; p += (size_t)n * 4 * 4;
    float* M    = (float*)p; p += (size_t)n * 4 * 4;
    float* DEN  = (float*)p; p += (size_t)n * 4 * 4;
    int* counts  = (int*)p; p += (size_t)n * 4;
    int* cursor  = (int*)p; p += (size_t)n * 4;
    int* offsets = (int*)p; p += (size_t)(n + 1) * 4;
    int* bsums   = (int*)p; p += 1024;
    int* csr_src = (int*)p; p += (size_t)etot * 4;

    const int eb = 256;
    const int egrid = (etot + eb - 1) / eb;
    const int nb = (n + 255) / 256;          // scan blocks (must be <= 256)
    const int ggrid = (n + 7) / 8;
    const int ngrid = (n + 3) / 4;

    // ---- CSR build (once; shared by both layers) ----
    hipMemsetAsync(counts, 0, (size_t)n * 4, stream);
    hist_dst<<<egrid, eb, 0, stream>>>(ei, counts, E, etot);
    scan1<<<nb, 256, 0, stream>>>(counts, offsets, bsums, n);
    scan2<<<1, 256, 0, stream>>>(bsums, nb);
    scan3<<<nb, 256, 0, stream>>>(offsets, bsums, cursor, n, etot);
    csr_fill<<<egrid, eb, 0, stream>>>(ei, cursor, csr_src, E, etot);

    // ---- layer 1 (H=4, C=32, concat) ----
    gemm_alpha<4><<<ggrid, 128, 0, stream>>>(x, W1, as1, ad1, bufA, AS, AD, n);
    node_mden<4><<<ngrid, 256, 0, stream>>>(offsets, csr_src, AS, AD, M, DEN, n);
    node_agg<4, 0><<<ngrid, 256, 0, stream>>>(offsets, csr_src, AS, AD, M, DEN,
                                              bufA, b1, bufB, n);  // bufB = elu(agg+b1)

    // ---- layer 2 (H=1, mean over 1 head = identity) ----
    gemm_alpha<1><<<ggrid, 128, 0, stream>>>(bufB, W2, as2, ad2, bufA, AS, AD, n);
    node_mden<1><<<ngrid, 256, 0, stream>>>(offsets, csr_src, AS, AD, M, DEN, n);
    node_agg<1, 1><<<ngrid, 256, 0, stream>>>(offsets, csr_src, AS, AD, M, DEN,
                                              bufA, b2, out, n);
}

// Round 3
// 296.436 us; speedup vs baseline: 6.5172x; 1.4885x over previous
//
#include <hip/hip_runtime.h>
#include <math.h>

typedef unsigned short u16;
typedef unsigned int u32;
typedef __attribute__((ext_vector_type(8))) short short8v;
typedef __attribute__((ext_vector_type(4))) float float4v;

__device__ __forceinline__ u16 f2bf(float f) {
    u32 u = __float_as_uint(f);
    u = (u + 0x7FFFu + ((u >> 16) & 1u)) >> 16;
    return (u16)u;
}
__device__ __forceinline__ float bflo(u32 u) { return __uint_as_float(u << 16); }
__device__ __forceinline__ float bfhi(u32 u) { return __uint_as_float(u & 0xFFFF0000u); }

// ---------------- weight prep: W [128][128] f32 -> WT [col][k] bf16 ----------
__global__ void prep_w(const float* __restrict__ W1, const float* __restrict__ W2,
                       u16* __restrict__ WT1, u16* __restrict__ WT2) {
    int t = blockIdx.x * 256 + threadIdx.x;   // 32768 total
    int which = t >> 14, idx = t & 16383;
    int k = idx >> 7, c = idx & 127;
    const float* W = which ? W2 : W1;
    u16* WT = which ? WT2 : WT1;
    WT[c * 128 + k] = f2bf(W[k * 128 + c]);
}

// ---------------- MFMA GEMM: Hb[n][128] (bf16) = X[n][128] @ W --------------
// A-frag: X row (lane&15), k = kk*32 + (lane>>4)*8 .. +7 (contiguous bf16x8)
// B-frag: WT row (lane&15) = output col, same k slice
// D: col = lane&15, row = 4*(lane>>4)+reg   [verified layout, learn_hip m89/m92]
template <int INBF16>
__global__ __launch_bounds__(256) void gemm_mfma(const void* __restrict__ Xv,
                                                 const u16* __restrict__ WT,
                                                 u16* __restrict__ Hb, int n) {
    __shared__ __align__(16) u16 xs[64][136];   // +8 pad: 272B row stride
    __shared__ __align__(16) u16 ws[128][136];
    const int t = threadIdx.x;
    const int n0 = blockIdx.x * 64;

    // stage WT (bf16 [128][128]) -> ws
    {
        const uint4* src = (const uint4*)WT;
        #pragma unroll
        for (int i = 0; i < 8; ++i) {
            int idx = t + i * 256;             // 2048 x 16B
            int row = idx >> 4, oct = idx & 15;
            uint4 v = src[idx];
            *(uint4*)&ws[row][oct * 8] = v;
        }
    }
    // stage X tile -> xs (convert to bf16 if needed)
    if (INBF16) {
        const u16* X = (const u16*)Xv;
        #pragma unroll
        for (int i = 0; i < 4; ++i) {
            int idx = t + i * 256;             // 1024 x 16B
            int row = idx >> 4, oct = idx & 15;
            uint4 v = make_uint4(0, 0, 0, 0);
            if (n0 + row < n) v = *(const uint4*)&X[(size_t)(n0 + row) * 128 + oct * 8];
            *(uint4*)&xs[row][oct * 8] = v;
        }
    } else {
        const float* X = (const float*)Xv;
        #pragma unroll
        for (int i = 0; i < 8; ++i) {
            int idx = t + i * 256;             // 2048 x float4
            int row = idx >> 5, quad = idx & 31;
            float4 v = make_float4(0.f, 0.f, 0.f, 0.f);
            if (n0 + row < n) v = *(const float4*)&X[(size_t)(n0 + row) * 128 + quad * 4];
            u32 lo = (u32)f2bf(v.x) | ((u32)f2bf(v.y) << 16);
            u32 hi = (u32)f2bf(v.z) | ((u32)f2bf(v.w) << 16);
            *(uint2*)&xs[row][quad * 4] = make_uint2(lo, hi);
        }
    }
    __syncthreads();

    const int wave = t >> 6, lane = t & 63;
    const int r0 = wave * 16;
    const int arow = r0 + (lane & 15);
    const int kb = (lane >> 4) * 8;

    float4v acc[8];
    #pragma unroll
    for (int j = 0; j < 8; ++j) acc[j] = (float4v){0.f, 0.f, 0.f, 0.f};

    #pragma unroll
    for (int kk = 0; kk < 4; ++kk) {
        const int k0 = kk * 32 + kb;
        short8v a = *(const short8v*)&xs[arow][k0];
        #pragma unroll
        for (int j = 0; j < 8; ++j) {
            short8v b = *(const short8v*)&ws[j * 16 + (lane & 15)][k0];
            acc[j] = __builtin_amdgcn_mfma_f32_16x16x32_bf16(a, b, acc[j], 0, 0, 0);
        }
    }

    const int rbase = n0 + r0 + (lane >> 4) * 4;
    #pragma unroll
    for (int j = 0; j < 8; ++j) {
        #pragma unroll
        for (int r = 0; r < 4; ++r) {
            int row = rbase + r;
            if (row < n) Hb[(size_t)row * 128 + j * 16 + (lane & 15)] = f2bf(acc[j][r]);
        }
    }
}

// ---------------- alpha_src/alpha_dst from bf16 h ----------------------------
template <int H>
__global__ void calc_alpha(const u16* __restrict__ Hb, const float* __restrict__ a_src,
                           const float* __restrict__ a_dst, float* __restrict__ AS,
                           float* __restrict__ AD, int n) {
    const int wid = threadIdx.x >> 6, lane = threadIdx.x & 63;
    const int d = blockIdx.x * 4 + wid;
    if (d >= n) return;
    const int c0 = lane * 2;
    u32 u = *(const u32*)&Hb[(size_t)d * 128 + c0];
    float h0 = bflo(u), h1 = bfhi(u);
    float vs = h0 * a_src[c0] + h1 * a_src[c0 + 1];
    float vd = h0 * a_dst[c0] + h1 * a_dst[c0 + 1];
    const int top = (H == 4) ? 8 : 32;
    #pragma unroll
    for (int o = 1; o <= top; o <<= 1) {
        vs += __shfl_xor(vs, o);
        vd += __shfl_xor(vd, o);
    }
    if (H == 4) {
        if ((lane & 15) == 0) { AS[d * 4 + (lane >> 4)] = vs; AD[d * 4 + (lane >> 4)] = vd; }
    } else {
        if (lane == 0) { AS[d] = vs; AD[d] = vd; }
    }
}

// ---------------- CSR build (counting sort by dst) ---------------------------
__global__ void hist_dst(const int* __restrict__ ei, int* __restrict__ counts,
                         int E, int etot) {
    int e = blockIdx.x * blockDim.x + threadIdx.x;
    if (e >= etot) return;
    int d = (e < E) ? ei[E + e] : e - E;
    atomicAdd(&counts[d], 1);
}

__global__ void scan1(const int* __restrict__ counts, int* __restrict__ offsets,
                      int* __restrict__ bsums, int n) {
    __shared__ int tmp[256];
    int tid = threadIdx.x;
    int i = blockIdx.x * 256 + tid;
    int v = (i < n) ? counts[i] : 0;
    tmp[tid] = v;
    __syncthreads();
    for (int off = 1; off < 256; off <<= 1) {
        int t = (tid >= off) ? tmp[tid - off] : 0;
        __syncthreads();
        tmp[tid] += t;
        __syncthreads();
    }
    if (i < n) offsets[i] = tmp[tid] - v;
    if (tid == 255) bsums[blockIdx.x] = tmp[255];
}

__global__ void scan2(int* __restrict__ bsums, int nb) {
    __shared__ int tmp[256];
    int tid = threadIdx.x;
    int v = (tid < nb) ? bsums[tid] : 0;
    tmp[tid] = v;
    __syncthreads();
    for (int off = 1; off < 256; off <<= 1) {
        int t = (tid >= off) ? tmp[tid - off] : 0;
        __syncthreads();
        tmp[tid] += t;
        __syncthreads();
    }
    if (tid < nb) bsums[tid] = tmp[tid] - v;
}

__global__ void scan3(int* __restrict__ offsets, const int* __restrict__ bsums,
                      int* __restrict__ cursor, int n, int etot) {
    int i = blockIdx.x * 256 + threadIdx.x;
    if (i < n) {
        int o = offsets[i] + bsums[blockIdx.x];
        offsets[i] = o;
        cursor[i] = o;
    }
    if (i == 0) offsets[n] = etot;
}

__global__ void csr_fill(const int* __restrict__ ei, int* __restrict__ cursor,
                         int* __restrict__ csr_src, int E, int etot) {
    int e = blockIdx.x * blockDim.x + threadIdx.x;
    if (e >= etot) return;
    int s, d;
    if (e < E) { s = ei[e]; d = ei[E + e]; } else { s = d = e - E; }
    int pos = atomicAdd(&cursor[d], 1);
    csr_src[pos] = s;
}

// ---------------- fused per-node softmax stats + gather aggregation ----------
// MODE 0: OUT is bf16, out = elu(agg + bias);  MODE 1: OUT is f32, out = agg + bias
template <int H, int MODE>
__global__ __launch_bounds__(256) void node_fused(
    const int* __restrict__ offsets, const int* __restrict__ csr_src,
    const float* __restrict__ AS, const float* __restrict__ AD,
    const u16* __restrict__ Hb, const float* __restrict__ bias,
    void* __restrict__ OUT, int n) {
    const int wid = threadIdx.x >> 6, lane = threadIdx.x & 63;
    const int d = blockIdx.x * 4 + wid;
    if (d >= n) return;
    const int off = offsets[d];
    const int deg = offsets[d + 1] - off;
    const int c0 = lane * 2;
    const int hh = (H == 4) ? (lane >> 4) : 0;

    float adv[H], mx[H], sm[H];
    #pragma unroll
    for (int h = 0; h < H; ++h) { adv[h] = AD[d * H + h]; mx[h] = -3.4e38f; sm[h] = 0.f; }

    // pass A: per-head max over incoming edges (lanes strided)
    for (int k = lane; k < deg; k += 64) {
        int s = csr_src[off + k];
        if (H == 4) {
            float4v a4 = *(const float4v*)&AS[s * 4];
            #pragma unroll
            for (int h = 0; h < 4; ++h) {
                float x = a4[h] + adv[h];
                mx[h] = fmaxf(mx[h], x > 0.f ? x : 0.2f * x);
            }
        } else {
            float x = AS[s] + adv[0];
            mx[0] = fmaxf(mx[0], x > 0.f ? x : 0.2f * x);
        }
    }
    #pragma unroll
    for (int h = 0; h < H; ++h)
        #pragma unroll
        for (int o = 32; o >= 1; o >>= 1) mx[h] = fmaxf(mx[h], __shfl_xor(mx[h], o));

    // pass B: per-head denominator
    for (int k = lane; k < deg; k += 64) {
        int s = csr_src[off + k];
        if (H == 4) {
            float4v a4 = *(const float4v*)&AS[s * 4];
            #pragma unroll
            for (int h = 0; h < 4; ++h) {
                float x = a4[h] + adv[h];
                float lr = x > 0.f ? x : 0.2f * x;
                sm[h] += __expf(lr - mx[h]);
            }
        } else {
            float x = AS[s] + adv[0];
            float lr = x > 0.f ? x : 0.2f * x;
            sm[0] += __expf(lr - mx[0]);
        }
    }
    #pragma unroll
    for (int h = 0; h < H; ++h)
        #pragma unroll
        for (int o = 32; o >= 1; o >>= 1) sm[h] += __shfl_xor(sm[h], o);

    const float madv = adv[hh];
    const float mmx = mx[hh];
    const float mdinv = 1.f / sm[hh];

    // phase 2: aggregation; alpha computed once per (edge,head) then shfl-broadcast
    constexpr int CH = (H == 4) ? 16 : 64;
    const int jme = (H == 4) ? (lane & 15) : lane;
    const int base = (H == 4) ? (lane & 48) : 0;
    float a0 = 0.f, a1 = 0.f;
    for (int k0 = 0; k0 < deg; k0 += CH) {
        int rem = min(CH, deg - k0);
        float a_l = 0.f;
        int s_l = 0;
        if (jme < rem) {
            int s = csr_src[off + k0 + jme];
            float x = AS[s * H + hh] + madv;
            float lr = x > 0.f ? x : 0.2f * x;
            a_l = __expf(lr - mmx) * mdinv;
            s_l = s;
        }
        for (int jj = 0; jj < rem; ++jj) {
            float al = __shfl(a_l, jj + base);
            int sj = __shfl(s_l, jj + base);
            u32 u = *(const u32*)&Hb[(size_t)sj * 128 + c0];
            a0 += al * bflo(u);
            a1 += al * bfhi(u);
        }
    }

    float o0 = a0 + bias[c0];
    float o1 = a1 + bias[c0 + 1];
    if (MODE == 0) {
        o0 = o0 > 0.f ? o0 : expm1f(o0);
        o1 = o1 > 0.f ? o1 : expm1f(o1);
        u32 pk = (u32)f2bf(o0) | ((u32)f2bf(o1) << 16);
        *(u32*)&((u16*)OUT)[(size_t)d * 128 + c0] = pk;
    } else {
        float* O = (float*)OUT;
        O[(size_t)d * 128 + c0] = o0;
        O[(size_t)d * 128 + c0 + 1] = o1;
    }
}

// ---------------- launch -----------------------------------------------------
extern "C" void kernel_launch(void* const* d_in, const int* in_sizes, int n_in,
                              void* d_out, int out_size, void* d_ws, size_t ws_size,
                              hipStream_t stream) {
    const float* x   = (const float*)d_in[0];
    const int*   ei  = (const int*)d_in[1];
    const float* W1  = (const float*)d_in[2];
    const float* as1 = (const float*)d_in[3];
    const float* ad1 = (const float*)d_in[4];
    const float* b1  = (const float*)d_in[5];
    const float* W2  = (const float*)d_in[6];
    const float* as2 = (const float*)d_in[7];
    const float* ad2 = (const float*)d_in[8];
    const float* b2  = (const float*)d_in[9];
    float* out = (float*)d_out;

    const int n = in_sizes[0] / 128;
    const int E = in_sizes[1] / 2;
    const int etot = E + n;

    char* p = (char*)d_ws;
    u16* Hb1 = (u16*)p; p += (size_t)n * 128 * 2;
    u16* Xb2 = (u16*)p; p += (size_t)n * 128 * 2;
    u16* Hb2 = (u16*)p; p += (size_t)n * 128 * 2;
    float* AS = (float*)p; p += (size_t)n * 4 * 4;
    float* AD = (float*)p; p += (size_t)n * 4 * 4;
    u16* WT1 = (u16*)p; p += 32768;
    u16* WT2 = (u16*)p; p += 32768;
    int* counts  = (int*)p; p += (size_t)n * 4;
    int* cursor  = (int*)p; p += (size_t)n * 4;
    int* csr_src = (int*)p; p += (size_t)etot * 4;
    int* offsets = (int*)p; p += (size_t)(n + 1) * 4;
    int* bsums   = (int*)p; p += 1024;

    const int eb = 256;
    const int egrid = (etot + eb - 1) / eb;
    const int nb = (n + 255) / 256;
    const int ggrid = (n + 63) / 64;
    const int ngrid = (n + 3) / 4;

    // weight prep + CSR build (shared by both layers)
    prep_w<<<128, 256, 0, stream>>>(W1, W2, WT1, WT2);
    hipMemsetAsync(counts, 0, (size_t)n * 4, stream);
    hist_dst<<<egrid, eb, 0, stream>>>(ei, counts, E, etot);
    scan1<<<nb, 256, 0, stream>>>(counts, offsets, bsums, n);
    scan2<<<1, 256, 0, stream>>>(bsums, nb);
    scan3<<<nb, 256, 0, stream>>>(offsets, bsums, cursor, n, etot);
    csr_fill<<<egrid, eb, 0, stream>>>(ei, cursor, csr_src, E, etot);

    // ---- layer 1 (H=4, concat, ELU fused) ----
    gemm_mfma<0><<<ggrid, 256, 0, stream>>>(x, WT1, Hb1, n);
    calc_alpha<4><<<ngrid, 256, 0, stream>>>(Hb1, as1, ad1, AS, AD, n);
    node_fused<4, 0><<<ngrid, 256, 0, stream>>>(offsets, csr_src, AS, AD, Hb1, b1, Xb2, n);

    // ---- layer 2 (H=1, mean over 1 head = identity) ----
    gemm_mfma<1><<<ggrid, 256, 0, stream>>>(Xb2, WT2, Hb2, n);
    calc_alpha<1><<<ngrid, 256, 0, stream>>>(Hb2, as2, ad2, AS, AD, n);
    node_fused<1, 1><<<ngrid, 256, 0, stream>>>(offsets, csr_src, AS, AD, Hb2, b2, out, n);
}

// Round 4
// 254.719 us; speedup vs baseline: 7.5845x; 1.1638x over previous
//
#include <hip/hip_runtime.h>
#include <math.h>

typedef unsigned short u16;
typedef unsigned int u32;
typedef __attribute__((ext_vector_type(8))) short short8v;
typedef __attribute__((ext_vector_type(4))) float float4v;

__device__ __forceinline__ u16 f2bf(float f) {
    u32 u = __float_as_uint(f);
    u = (u + 0x7FFFu + ((u >> 16) & 1u)) >> 16;
    return (u16)u;
}
__device__ __forceinline__ float bflo(u32 u) { return __uint_as_float(u << 16); }
__device__ __forceinline__ float bfhi(u32 u) { return __uint_as_float(u & 0xFFFF0000u); }

// ---------------- weight prep: W [128][128] f32 -> WT [col][k] bf16 ----------
__global__ void prep_w(const float* __restrict__ W1, const float* __restrict__ W2,
                       u16* __restrict__ WT1, u16* __restrict__ WT2) {
    int t = blockIdx.x * 256 + threadIdx.x;   // 32768 total
    int which = t >> 14, idx = t & 16383;
    int k = idx >> 7, c = idx & 127;
    const float* W = which ? W2 : W1;
    u16* WT = which ? WT2 : WT1;
    WT[c * 128 + k] = f2bf(W[k * 128 + c]);
}

// ---------------- MFMA GEMM + fused alpha_src/alpha_dst ---------------------
// Hb[n][128](bf16) = X[n][128] @ W ; AS/AD[n][H] from f32 acc registers.
// A-frag: X row (lane&15), k=kk*32+(lane>>4)*8..+7 ; B-frag: WT row = out col.
// D: col = lane&15, row = 4*(lane>>4)+reg  [verified, learn_hip m89/m92]
template <int INBF16, int H>
__global__ __launch_bounds__(256) void gemm_mfma(const void* __restrict__ Xv,
                                                 const u16* __restrict__ WT,
                                                 const float* __restrict__ a_src,
                                                 const float* __restrict__ a_dst,
                                                 u16* __restrict__ Hb,
                                                 float* __restrict__ AS,
                                                 float* __restrict__ AD, int n) {
    __shared__ __align__(16) u16 xs[64][136];
    __shared__ __align__(16) u16 ws[128][136];
    const int t = threadIdx.x;
    const int n0 = blockIdx.x * 64;

    {
        const uint4* src = (const uint4*)WT;
        #pragma unroll
        for (int i = 0; i < 8; ++i) {
            int idx = t + i * 256;
            int row = idx >> 4, oct = idx & 15;
            uint4 v = src[idx];
            *(uint4*)&ws[row][oct * 8] = v;
        }
    }
    if (INBF16) {
        const u16* X = (const u16*)Xv;
        #pragma unroll
        for (int i = 0; i < 4; ++i) {
            int idx = t + i * 256;
            int row = idx >> 4, oct = idx & 15;
            uint4 v = make_uint4(0, 0, 0, 0);
            if (n0 + row < n) v = *(const uint4*)&X[(size_t)(n0 + row) * 128 + oct * 8];
            *(uint4*)&xs[row][oct * 8] = v;
        }
    } else {
        const float* X = (const float*)Xv;
        #pragma unroll
        for (int i = 0; i < 8; ++i) {
            int idx = t + i * 256;
            int row = idx >> 5, quad = idx & 31;
            float4 v = make_float4(0.f, 0.f, 0.f, 0.f);
            if (n0 + row < n) v = *(const float4*)&X[(size_t)(n0 + row) * 128 + quad * 4];
            u32 lo = (u32)f2bf(v.x) | ((u32)f2bf(v.y) << 16);
            u32 hi = (u32)f2bf(v.z) | ((u32)f2bf(v.w) << 16);
            *(uint2*)&xs[row][quad * 4] = make_uint2(lo, hi);
        }
    }
    __syncthreads();

    const int wave = t >> 6, lane = t & 63;
    const int r0 = wave * 16;
    const int kcol = lane & 15;
    const int arow = r0 + kcol;
    const int kb = (lane >> 4) * 8;

    float4v acc[8];
    #pragma unroll
    for (int j = 0; j < 8; ++j) acc[j] = (float4v){0.f, 0.f, 0.f, 0.f};

    #pragma unroll
    for (int kk = 0; kk < 4; ++kk) {
        const int k0 = kk * 32 + kb;
        short8v a = *(const short8v*)&xs[arow][k0];
        #pragma unroll
        for (int j = 0; j < 8; ++j) {
            short8v b = *(const short8v*)&ws[j * 16 + kcol][k0];
            acc[j] = __builtin_amdgcn_mfma_f32_16x16x32_bf16(a, b, acc[j], 0, 0, 0);
        }
    }

    // store Hb
    const int rbase = n0 + r0 + (lane >> 4) * 4;
    #pragma unroll
    for (int j = 0; j < 8; ++j) {
        #pragma unroll
        for (int r = 0; r < 4; ++r) {
            int row = rbase + r;
            if (row < n) Hb[(size_t)row * 128 + j * 16 + kcol] = f2bf(acc[j][r]);
        }
    }

    // fused AS/AD epilogue (from f32 acc)
    float av[8], bv[8];
    #pragma unroll
    for (int j = 0; j < 8; ++j) {
        av[j] = a_src[j * 16 + kcol];
        bv[j] = a_dst[j * 16 + kcol];
    }

    if (H == 4) {
        float ps[4][4], pd[4][4];
        #pragma unroll
        for (int r = 0; r < 4; ++r)
            #pragma unroll
            for (int h = 0; h < 4; ++h) {
                ps[r][h] = acc[2*h][r] * av[2*h] + acc[2*h+1][r] * av[2*h+1];
                pd[r][h] = acc[2*h][r] * bv[2*h] + acc[2*h+1][r] * bv[2*h+1];
            }
        #pragma unroll
        for (int o = 8; o >= 1; o >>= 1)
            #pragma unroll
            for (int r = 0; r < 4; ++r)
                #pragma unroll
                for (int h = 0; h < 4; ++h) {
                    ps[r][h] += __shfl_xor(ps[r][h], o);
                    pd[r][h] += __shfl_xor(pd[r][h], o);
                }
        float wvs = 0.f, wvd = 0.f;
        #pragma unroll
        for (int r = 0; r < 4; ++r)
            #pragma unroll
            for (int h = 0; h < 4; ++h)
                if (kcol == r * 4 + h) { wvs = ps[r][h]; wvd = pd[r][h]; }
        int node = rbase + (kcol >> 2);
        if (node < n) {
            AS[node * 4 + (kcol & 3)] = wvs;
            AD[node * 4 + (kcol & 3)] = wvd;
        }
    } else {
        float ps[4], pd[4];
        #pragma unroll
        for (int r = 0; r < 4; ++r) {
            float s_ = 0.f, d_ = 0.f;
            #pragma unroll
            for (int j = 0; j < 8; ++j) {
                s_ += acc[j][r] * av[j];
                d_ += acc[j][r] * bv[j];
            }
            ps[r] = s_; pd[r] = d_;
        }
        #pragma unroll
        for (int o = 8; o >= 1; o >>= 1)
            #pragma unroll
            for (int r = 0; r < 4; ++r) {
                ps[r] += __shfl_xor(ps[r], o);
                pd[r] += __shfl_xor(pd[r], o);
            }
        float val = 0.f;
        #pragma unroll
        for (int r = 0; r < 4; ++r)
            if ((kcol & 3) == r) val = (kcol < 4) ? ps[r] : pd[r];
        int node = rbase + (kcol & 3);
        if (kcol < 8 && node < n) {
            if (kcol < 4) AS[node] = val;
            else          AD[node] = val;
        }
    }
}

// ---------------- CSR build (counting sort by dst) ---------------------------
__global__ void hist_dst(const int* __restrict__ ei, int* __restrict__ counts,
                         int E, int etot) {
    int e = blockIdx.x * blockDim.x + threadIdx.x;
    if (e >= etot) return;
    int d = (e < E) ? ei[E + e] : e - E;
    atomicAdd(&counts[d], 1);
}

__global__ void scan1(const int* __restrict__ counts, int* __restrict__ offsets,
                      int* __restrict__ bsums, int n) {
    __shared__ int tmp[256];
    int tid = threadIdx.x;
    int i = blockIdx.x * 256 + tid;
    int v = (i < n) ? counts[i] : 0;
    tmp[tid] = v;
    __syncthreads();
    for (int off = 1; off < 256; off <<= 1) {
        int t = (tid >= off) ? tmp[tid - off] : 0;
        __syncthreads();
        tmp[tid] += t;
        __syncthreads();
    }
    if (i < n) offsets[i] = tmp[tid] - v;
    if (tid == 255) bsums[blockIdx.x] = tmp[255];
}

__global__ void scan2(int* __restrict__ bsums, int nb) {
    __shared__ int tmp[256];
    int tid = threadIdx.x;
    int v = (tid < nb) ? bsums[tid] : 0;
    tmp[tid] = v;
    __syncthreads();
    for (int off = 1; off < 256; off <<= 1) {
        int t = (tid >= off) ? tmp[tid - off] : 0;
        __syncthreads();
        tmp[tid] += t;
        __syncthreads();
    }
    if (tid < nb) bsums[tid] = tmp[tid] - v;
}

__global__ void scan3(int* __restrict__ offsets, const int* __restrict__ bsums,
                      int* __restrict__ cursor, int n, int etot) {
    int i = blockIdx.x * 256 + threadIdx.x;
    if (i < n) {
        int o = offsets[i] + bsums[blockIdx.x];
        offsets[i] = o;
        cursor[i] = o;
    }
    if (i == 0) offsets[n] = etot;
}

__global__ void csr_fill(const int* __restrict__ ei, int* __restrict__ cursor,
                         int* __restrict__ csr_src, int E, int etot) {
    int e = blockIdx.x * blockDim.x + threadIdx.x;
    if (e >= etot) return;
    int s, d;
    if (e < E) { s = ei[e]; d = ei[E + e]; } else { s = d = e - E; }
    int pos = atomicAdd(&cursor[d], 1);
    csr_src[pos] = s;
}

// ---------------- fused per-node softmax stats + gather aggregation ----------
// One wave per node. Stats: lane = head*16 + slot (H=4) or lane = slot (H=1);
// lane-local accumulate across chunks, single butterfly per pass.
// Agg: alpha per (edge,head) on stats lanes, shfl-broadcast; full 16-edge
// chunks take a fully-unrolled path (ILP hides gather latency).
// MODE 0: OUT bf16, elu(agg+bias);  MODE 1: OUT f32, agg+bias.
template <int H, int MODE>
__global__ __launch_bounds__(256) void node_fused(
    const int* __restrict__ offsets, const int* __restrict__ csr_src,
    const float* __restrict__ AS, const float* __restrict__ AD,
    const u16* __restrict__ Hb, const float* __restrict__ bias,
    void* __restrict__ OUT, int n) {
    const int wid = threadIdx.x >> 6, lane = threadIdx.x & 63;
    const int d = blockIdx.x * 4 + wid;
    if (d >= n) return;
    const int off = offsets[d];
    const int deg = offsets[d + 1] - off;
    const int g   = (H == 4) ? (lane >> 4) : 0;   // head owned by this lane
    const int j16 = (H == 4) ? (lane & 15) : lane; // edge slot in stats chunk
    constexpr int SCH = (H == 4) ? 16 : 64;        // stats/alpha chunk size

    const float adv = AD[d * H + g];

    // pass A: running max (lane-local, then one butterfly)
    float mxp = -3.4e38f;
    for (int k0 = 0; k0 < deg; k0 += SCH) {
        int k = k0 + j16;
        if (k < deg) {
            int s = csr_src[off + k];
            float x = AS[s * H + g] + adv;
            mxp = fmaxf(mxp, x > 0.f ? x : 0.2f * x);
        }
    }
    #pragma unroll
    for (int o = (H == 4 ? 8 : 32); o >= 1; o >>= 1)
        mxp = fmaxf(mxp, __shfl_xor(mxp, o));
    const float mx = mxp;

    // pass B: denominator
    float smp = 0.f;
    for (int k0 = 0; k0 < deg; k0 += SCH) {
        int k = k0 + j16;
        if (k < deg) {
            int s = csr_src[off + k];
            float x = AS[s * H + g] + adv;
            float lr = x > 0.f ? x : 0.2f * x;
            smp += __expf(lr - mx);
        }
    }
    #pragma unroll
    for (int o = (H == 4 ? 8 : 32); o >= 1; o >>= 1)
        smp += __shfl_xor(smp, o);
    const float dinv = 1.f / smp;

    // aggregation
    const int c0 = lane * 2;
    const int base = (H == 4) ? (lane & 48) : 0;
    float a0 = 0.f, a1 = 0.f;
    for (int k0 = 0; k0 < deg; k0 += SCH) {
        int rem = min(SCH, deg - k0);
        float a_l = 0.f;
        int s_l = 0;
        if (j16 < rem) {
            int s = csr_src[off + k0 + j16];
            float x = AS[s * H + g] + adv;
            float lr = x > 0.f ? x : 0.2f * x;
            a_l = __expf(lr - mx) * dinv;
            s_l = s;
        }
        for (int q = 0; q < rem; q += 16) {
            int r2 = min(16, rem - q);
            if (r2 == 16) {
                #pragma unroll
                for (int jj = 0; jj < 16; ++jj) {
                    float al = __shfl(a_l, base + q + jj);
                    int  sj  = __shfl(s_l, base + q + jj);
                    u32 u = *(const u32*)&Hb[(size_t)sj * 128 + c0];
                    a0 += al * bflo(u);
                    a1 += al * bfhi(u);
                }
            } else {
                for (int jj = 0; jj < r2; ++jj) {
                    float al = __shfl(a_l, base + q + jj);
                    int  sj  = __shfl(s_l, base + q + jj);
                    u32 u = *(const u32*)&Hb[(size_t)sj * 128 + c0];
                    a0 += al * bflo(u);
                    a1 += al * bfhi(u);
                }
            }
        }
    }

    float o0 = a0 + bias[c0];
    float o1 = a1 + bias[c0 + 1];
    if (MODE == 0) {
        o0 = o0 > 0.f ? o0 : expm1f(o0);
        o1 = o1 > 0.f ? o1 : expm1f(o1);
        u32 pk = (u32)f2bf(o0) | ((u32)f2bf(o1) << 16);
        *(u32*)&((u16*)OUT)[(size_t)d * 128 + c0] = pk;
    } else {
        float* O = (float*)OUT;
        O[(size_t)d * 128 + c0] = o0;
        O[(size_t)d * 128 + c0 + 1] = o1;
    }
}

// ---------------- launch -----------------------------------------------------
extern "C" void kernel_launch(void* const* d_in, const int* in_sizes, int n_in,
                              void* d_out, int out_size, void* d_ws, size_t ws_size,
                              hipStream_t stream) {
    const float* x   = (const float*)d_in[0];
    const int*   ei  = (const int*)d_in[1];
    const float* W1  = (const float*)d_in[2];
    const float* as1 = (const float*)d_in[3];
    const float* ad1 = (const float*)d_in[4];
    const float* b1  = (const float*)d_in[5];
    const float* W2  = (const float*)d_in[6];
    const float* as2 = (const float*)d_in[7];
    const float* ad2 = (const float*)d_in[8];
    const float* b2  = (const float*)d_in[9];
    float* out = (float*)d_out;

    const int n = in_sizes[0] / 128;
    const int E = in_sizes[1] / 2;
    const int etot = E + n;

    char* p = (char*)d_ws;
    u16* Hb1 = (u16*)p; p += (size_t)n * 128 * 2;
    u16* Xb2 = (u16*)p; p += (size_t)n * 128 * 2;
    u16* Hb2 = (u16*)p; p += (size_t)n * 128 * 2;
    float* AS = (float*)p; p += (size_t)n * 4 * 4;
    float* AD = (float*)p; p += (size_t)n * 4 * 4;
    u16* WT1 = (u16*)p; p += 32768;
    u16* WT2 = (u16*)p; p += 32768;
    int* counts  = (int*)p; p += (size_t)n * 4;
    int* cursor  = (int*)p; p += (size_t)n * 4;
    int* csr_src = (int*)p; p += (size_t)etot * 4;
    int* offsets = (int*)p; p += (size_t)(n + 1) * 4;
    int* bsums   = (int*)p; p += 1024;

    const int eb = 256;
    const int egrid = (etot + eb - 1) / eb;
    const int nb = (n + 255) / 256;
    const int ggrid = (n + 63) / 64;
    const int ngrid = (n + 3) / 4;

    // weight prep + CSR build (shared by both layers)
    prep_w<<<128, 256, 0, stream>>>(W1, W2, WT1, WT2);
    hipMemsetAsync(counts, 0, (size_t)n * 4, stream);
    hist_dst<<<egrid, eb, 0, stream>>>(ei, counts, E, etot);
    scan1<<<nb, 256, 0, stream>>>(counts, offsets, bsums, n);
    scan2<<<1, 256, 0, stream>>>(bsums, nb);
    scan3<<<nb, 256, 0, stream>>>(offsets, bsums, cursor, n, etot);
    csr_fill<<<egrid, eb, 0, stream>>>(ei, cursor, csr_src, E, etot);

    // ---- layer 1 (H=4, concat, ELU fused) ----
    gemm_mfma<0, 4><<<ggrid, 256, 0, stream>>>(x, WT1, as1, ad1, Hb1, AS, AD, n);
    node_fused<4, 0><<<ngrid, 256, 0, stream>>>(offsets, csr_src, AS, AD, Hb1, b1, Xb2, n);

    // ---- layer 2 (H=1, mean over 1 head = identity) ----
    gemm_mfma<1, 1><<<ggrid, 256, 0, stream>>>(Xb2, WT2, as2, ad2, Hb2, AS, AD, n);
    node_fused<1, 1><<<ngrid, 256, 0, stream>>>(offsets, csr_src, AS, AD, Hb2, b2, out, n);
}

// Round 6
// 227.115 us; speedup vs baseline: 8.5064x; 1.1215x over previous
//
#include <hip/hip_runtime.h>
#include <math.h>

typedef unsigned short u16;
typedef unsigned int u32;
typedef __attribute__((ext_vector_type(8))) short short8v;
typedef __attribute__((ext_vector_type(4))) float float4v;

__device__ __forceinline__ u16 f2bf(float f) {
    u32 u = __float_as_uint(f);
    u = (u + 0x7FFFu + ((u >> 16) & 1u)) >> 16;
    return (u16)u;
}
__device__ __forceinline__ float bflo(u32 u) { return __uint_as_float(u << 16); }
__device__ __forceinline__ float bfhi(u32 u) { return __uint_as_float(u & 0xFFFF0000u); }

// ---------------- weight prep: W [128][128] f32 -> WT [col][k] bf16 ----------
__global__ void prep_w(const float* __restrict__ W1, const float* __restrict__ W2,
                       u16* __restrict__ WT1, u16* __restrict__ WT2) {
    int t = blockIdx.x * 256 + threadIdx.x;   // 32768 total
    int which = t >> 14, idx = t & 16383;
    int k = idx >> 7, c = idx & 127;
    const float* W = which ? W2 : W1;
    u16* WT = which ? WT2 : WT1;
    WT[c * 128 + k] = f2bf(W[k * 128 + c]);
}

// ---------------- MFMA GEMM + fused alpha_src/alpha_dst ---------------------
template <int INBF16, int H>
__global__ __launch_bounds__(256) void gemm_mfma(const void* __restrict__ Xv,
                                                 const u16* __restrict__ WT,
                                                 const float* __restrict__ a_src,
                                                 const float* __restrict__ a_dst,
                                                 u16* __restrict__ Hb,
                                                 float* __restrict__ AS,
                                                 float* __restrict__ AD, int n) {
    __shared__ __align__(16) u16 xs[64][136];
    __shared__ __align__(16) u16 ws[128][136];
    const int t = threadIdx.x;
    const int n0 = blockIdx.x * 64;

    {
        const uint4* src = (const uint4*)WT;
        #pragma unroll
        for (int i = 0; i < 8; ++i) {
            int idx = t + i * 256;
            int row = idx >> 4, oct = idx & 15;
            uint4 v = src[idx];
            *(uint4*)&ws[row][oct * 8] = v;
        }
    }
    if (INBF16) {
        const u16* X = (const u16*)Xv;
        #pragma unroll
        for (int i = 0; i < 4; ++i) {
            int idx = t + i * 256;
            int row = idx >> 4, oct = idx & 15;
            uint4 v = make_uint4(0, 0, 0, 0);
            if (n0 + row < n) v = *(const uint4*)&X[(size_t)(n0 + row) * 128 + oct * 8];
            *(uint4*)&xs[row][oct * 8] = v;
        }
    } else {
        const float* X = (const float*)Xv;
        #pragma unroll
        for (int i = 0; i < 8; ++i) {
            int idx = t + i * 256;
            int row = idx >> 5, quad = idx & 31;
            float4 v = make_float4(0.f, 0.f, 0.f, 0.f);
            if (n0 + row < n) v = *(const float4*)&X[(size_t)(n0 + row) * 128 + quad * 4];
            u32 lo = (u32)f2bf(v.x) | ((u32)f2bf(v.y) << 16);
            u32 hi = (u32)f2bf(v.z) | ((u32)f2bf(v.w) << 16);
            *(uint2*)&xs[row][quad * 4] = make_uint2(lo, hi);
        }
    }
    __syncthreads();

    const int wave = t >> 6, lane = t & 63;
    const int r0 = wave * 16;
    const int kcol = lane & 15;
    const int arow = r0 + kcol;
    const int kb = (lane >> 4) * 8;

    float4v acc[8];
    #pragma unroll
    for (int j = 0; j < 8; ++j) acc[j] = (float4v){0.f, 0.f, 0.f, 0.f};

    #pragma unroll
    for (int kk = 0; kk < 4; ++kk) {
        const int k0 = kk * 32 + kb;
        short8v a = *(const short8v*)&xs[arow][k0];
        #pragma unroll
        for (int j = 0; j < 8; ++j) {
            short8v b = *(const short8v*)&ws[j * 16 + kcol][k0];
            acc[j] = __builtin_amdgcn_mfma_f32_16x16x32_bf16(a, b, acc[j], 0, 0, 0);
        }
    }

    const int rbase = n0 + r0 + (lane >> 4) * 4;
    #pragma unroll
    for (int j = 0; j < 8; ++j) {
        #pragma unroll
        for (int r = 0; r < 4; ++r) {
            int row = rbase + r;
            if (row < n) Hb[(size_t)row * 128 + j * 16 + kcol] = f2bf(acc[j][r]);
        }
    }

    float av[8], bv[8];
    #pragma unroll
    for (int j = 0; j < 8; ++j) {
        av[j] = a_src[j * 16 + kcol];
        bv[j] = a_dst[j * 16 + kcol];
    }

    if (H == 4) {
        float ps[4][4], pd[4][4];
        #pragma unroll
        for (int r = 0; r < 4; ++r)
            #pragma unroll
            for (int h = 0; h < 4; ++h) {
                ps[r][h] = acc[2*h][r] * av[2*h] + acc[2*h+1][r] * av[2*h+1];
                pd[r][h] = acc[2*h][r] * bv[2*h] + acc[2*h+1][r] * bv[2*h+1];
            }
        #pragma unroll
        for (int o = 8; o >= 1; o >>= 1)
            #pragma unroll
            for (int r = 0; r < 4; ++r)
                #pragma unroll
                for (int h = 0; h < 4; ++h) {
                    ps[r][h] += __shfl_xor(ps[r][h], o);
                    pd[r][h] += __shfl_xor(pd[r][h], o);
                }
        float wvs = 0.f, wvd = 0.f;
        #pragma unroll
        for (int r = 0; r < 4; ++r)
            #pragma unroll
            for (int h = 0; h < 4; ++h)
                if (kcol == r * 4 + h) { wvs = ps[r][h]; wvd = pd[r][h]; }
        int node = rbase + (kcol >> 2);
        if (node < n) {
            AS[node * 4 + (kcol & 3)] = wvs;
            AD[node * 4 + (kcol & 3)] = wvd;
        }
    } else {
        float ps[4], pd[4];
        #pragma unroll
        for (int r = 0; r < 4; ++r) {
            float s_ = 0.f, d_ = 0.f;
            #pragma unroll
            for (int j = 0; j < 8; ++j) {
                s_ += acc[j][r] * av[j];
                d_ += acc[j][r] * bv[j];
            }
            ps[r] = s_; pd[r] = d_;
        }
        #pragma unroll
        for (int o = 8; o >= 1; o >>= 1)
            #pragma unroll
            for (int r = 0; r < 4; ++r) {
                ps[r] += __shfl_xor(ps[r], o);
                pd[r] += __shfl_xor(pd[r], o);
            }
        float val = 0.f;
        #pragma unroll
        for (int r = 0; r < 4; ++r)
            if ((kcol & 3) == r) val = (kcol < 4) ? ps[r] : pd[r];
        int node = rbase + (kcol & 3);
        if (kcol < 8 && node < n) {
            if (kcol < 4) AS[node] = val;
            else          AD[node] = val;
        }
    }
}

// ---------------- CSR build (counting sort by dst) ---------------------------
__global__ void hist_dst(const int* __restrict__ ei, int* __restrict__ counts,
                         int E, int etot) {
    int e = blockIdx.x * blockDim.x + threadIdx.x;
    if (e >= etot) return;
    int d = (e < E) ? ei[E + e] : e - E;
    atomicAdd(&counts[d], 1);
}

__global__ void scan1(const int* __restrict__ counts, int* __restrict__ offsets,
                      int* __restrict__ bsums, int n) {
    __shared__ int tmp[256];
    int tid = threadIdx.x;
    int i = blockIdx.x * 256 + tid;
    int v = (i < n) ? counts[i] : 0;
    tmp[tid] = v;
    __syncthreads();
    for (int off = 1; off < 256; off <<= 1) {
        int t = (tid >= off) ? tmp[tid - off] : 0;
        __syncthreads();
        tmp[tid] += t;
        __syncthreads();
    }
    if (i < n) offsets[i] = tmp[tid] - v;
    if (tid == 255) bsums[blockIdx.x] = tmp[255];
}

__global__ void scan2(int* __restrict__ bsums, int nb) {
    __shared__ int tmp[256];
    int tid = threadIdx.x;
    int v = (tid < nb) ? bsums[tid] : 0;
    tmp[tid] = v;
    __syncthreads();
    for (int off = 1; off < 256; off <<= 1) {
        int t = (tid >= off) ? tmp[tid - off] : 0;
        __syncthreads();
        tmp[tid] += t;
        __syncthreads();
    }
    if (tid < nb) bsums[tid] = tmp[tid] - v;
}

__global__ void scan3(int* __restrict__ offsets, const int* __restrict__ bsums,
                      int* __restrict__ cursor, int n, int etot) {
    int i = blockIdx.x * 256 + threadIdx.x;
    if (i < n) {
        int o = offsets[i] + bsums[blockIdx.x];
        offsets[i] = o;
        cursor[i] = o;
    }
    if (i == 0) offsets[n] = etot;
}

__global__ void csr_fill(const int* __restrict__ ei, int* __restrict__ cursor,
                         int* __restrict__ csr_src, int E, int etot) {
    int e = blockIdx.x * blockDim.x + threadIdx.x;
    if (e >= etot) return;
    int s, d;
    if (e < E) { s = ei[e]; d = ei[E + e]; } else { s = d = e - E; }
    int pos = atomicAdd(&cursor[d], 1);
    csr_src[pos] = s;
}

// ---------------- single-pass fused softmax + aggregation --------------------
// One wave per node. NO max subtraction (|logit| ~ O(8), exp safe in f32) and
// deferred normalization: acc = sum exp(e)*h ; sm = sum exp(e) ; out = acc/sm.
// Alpha lanes: lane = head*16 + slot (H=4) / lane = slot (H=1), one exp per
// (edge,head). Gather: 2 edges per wave-load -- lane loads 8B (4 channels) of
// edge (2p + lane>>5); parity partials combined via shfl_xor(32) at the end.
// MODE 0: OUT bf16, elu(agg+bias);  MODE 1: OUT f32, agg+bias.
template <int H, int MODE>
__global__ __launch_bounds__(256) void node_fused(
    const int* __restrict__ offsets, const int* __restrict__ csr_src,
    const float* __restrict__ AS, const float* __restrict__ AD,
    const u16* __restrict__ Hb, const float* __restrict__ bias,
    void* __restrict__ OUT, int n) {
    const int wid = threadIdx.x >> 6, lane = threadIdx.x & 63;
    const int d = blockIdx.x * 4 + wid;
    if (d >= n) return;
    const int off = offsets[d];
    const int deg = offsets[d + 1] - off;

    constexpr int SCH = (H == 4) ? 16 : 64;        // edges per chunk
    const int slot = (H == 4) ? (lane & 15) : lane; // alpha slot
    const int g    = (H == 4) ? (lane >> 4) : 0;    // head this lane's alpha covers
    const float adv = AD[d * H + g];

    const int which = lane >> 5;                    // edge parity in pair
    const int cq    = lane & 31;                    // my 4 channels: 4cq..4cq+3
    const int ghead = (H == 4) ? (cq >> 3) : 0;     // head of my channels

    float acc0 = 0.f, acc1 = 0.f, acc2 = 0.f, acc3 = 0.f;
    float smp = 0.f;

    // prefetch chunk 0 alpha inputs
    bool v = slot < deg;
    int   s_cur = v ? csr_src[off + slot] : 0;
    float x_cur = v ? AS[s_cur * H + g] : 0.f;
    float vm_cur = v ? 1.f : 0.f;

    for (int k0 = 0; k0 < deg; k0 += SCH) {
        // prefetch next chunk (loads overlap current chunk's gather)
        int kn = k0 + SCH + slot;
        bool vn = kn < deg;
        int   s_nxt = vn ? csr_src[off + kn] : 0;
        float x_nxt = vn ? AS[s_nxt * H + g] : 0.f;

        float e = x_cur + adv;
        float lr = e > 0.f ? e : 0.2f * e;
        float a_l = vm_cur * __expf(lr);
        smp += a_l;

        const int rem = min(SCH, deg - k0);
        const int npairs = (rem + 1) >> 1;
        #pragma unroll
        for (int p = 0; p < SCH / 2; ++p) {
            if (p >= npairs) break;                 // wave-uniform branch
            int eslot = p * 2 + which;
            int aidx = (H == 4) ? (ghead * 16 + eslot) : eslot;
            float al = __shfl(a_l, aidx);
            int   sj = __shfl(s_cur, aidx);
            uint2 u2 = *(const uint2*)&Hb[(size_t)sj * 128 + cq * 4];
            acc0 += al * bflo(u2.x);
            acc1 += al * bfhi(u2.x);
            acc2 += al * bflo(u2.y);
            acc3 += al * bfhi(u2.y);
        }
        s_cur = s_nxt; x_cur = x_nxt; vm_cur = vn ? 1.f : 0.f;
    }

    // denominator: butterfly over slots (per head for H=4), then route to my head
    #pragma unroll
    for (int o = (H == 4 ? 8 : 32); o >= 1; o >>= 1)
        smp += __shfl_xor(smp, o);
    float den = (H == 4) ? __shfl(smp, ghead * 16) : smp;
    const float dinv = 1.f / den;

    // combine pair-parity partials
    acc0 += __shfl_xor(acc0, 32);
    acc1 += __shfl_xor(acc1, 32);
    acc2 += __shfl_xor(acc2, 32);
    acc3 += __shfl_xor(acc3, 32);

    if (lane < 32) {
        const float4 bv = *(const float4*)&bias[cq * 4];
        float o0 = acc0 * dinv + bv.x;
        float o1 = acc1 * dinv + bv.y;
        float o2 = acc2 * dinv + bv.z;
        float o3 = acc3 * dinv + bv.w;
        if (MODE == 0) {
            o0 = o0 > 0.f ? o0 : expm1f(o0);
            o1 = o1 > 0.f ? o1 : expm1f(o1);
            o2 = o2 > 0.f ? o2 : expm1f(o2);
            o3 = o3 > 0.f ? o3 : expm1f(o3);
            uint2 pk;
            pk.x = (u32)f2bf(o0) | ((u32)f2bf(o1) << 16);
            pk.y = (u32)f2bf(o2) | ((u32)f2bf(o3) << 16);
            *(uint2*)&((u16*)OUT)[(size_t)d * 128 + cq * 4] = pk;
        } else {
            float* O = (float*)OUT;
            *(float4*)&O[(size_t)d * 128 + cq * 4] = make_float4(o0, o1, o2, o3);
        }
    }
}

// ---------------- launch -----------------------------------------------------
extern "C" void kernel_launch(void* const* d_in, const int* in_sizes, int n_in,
                              void* d_out, int out_size, void* d_ws, size_t ws_size,
                              hipStream_t stream) {
    const float* x   = (const float*)d_in[0];
    const int*   ei  = (const int*)d_in[1];
    const float* W1  = (const float*)d_in[2];
    const float* as1 = (const float*)d_in[3];
    const float* ad1 = (const float*)d_in[4];
    const float* b1  = (const float*)d_in[5];
    const float* W2  = (const float*)d_in[6];
    const float* as2 = (const float*)d_in[7];
    const float* ad2 = (const float*)d_in[8];
    const float* b2  = (const float*)d_in[9];
    float* out = (float*)d_out;

    const int n = in_sizes[0] / 128;
    const int E = in_sizes[1] / 2;
    const int etot = E + n;

    char* p = (char*)d_ws;
    u16* Hb1 = (u16*)p; p += (size_t)n * 128 * 2;
    u16* Xb2 = (u16*)p; p += (size_t)n * 128 * 2;
    u16* Hb2 = (u16*)p; p += (size_t)n * 128 * 2;
    float* AS = (float*)p; p += (size_t)n * 4 * 4;
    float* AD = (float*)p; p += (size_t)n * 4 * 4;
    u16* WT1 = (u16*)p; p += 32768;
    u16* WT2 = (u16*)p; p += 32768;
    int* counts  = (int*)p; p += (size_t)n * 4;
    int* cursor  = (int*)p; p += (size_t)n * 4;
    int* csr_src = (int*)p; p += (size_t)etot * 4;
    int* offsets = (int*)p; p += (size_t)(n + 1) * 4;
    int* bsums   = (int*)p; p += 1024;

    const int eb = 256;
    const int egrid = (etot + eb - 1) / eb;
    const int nb = (n + 255) / 256;
    const int ggrid = (n + 63) / 64;
    const int ngrid = (n + 3) / 4;

    prep_w<<<128, 256, 0, stream>>>(W1, W2, WT1, WT2);
    (void)hipMemsetAsync(counts, 0, (size_t)n * 4, stream);
    hist_dst<<<egrid, eb, 0, stream>>>(ei, counts, E, etot);
    scan1<<<nb, 256, 0, stream>>>(counts, offsets, bsums, n);
    scan2<<<1, 256, 0, stream>>>(bsums, nb);
    scan3<<<nb, 256, 0, stream>>>(offsets, bsums, cursor, n, etot);
    csr_fill<<<egrid, eb, 0, stream>>>(ei, cursor, csr_src, E, etot);

    // ---- layer 1 (H=4, concat, ELU fused) ----
    gemm_mfma<0, 4><<<ggrid, 256, 0, stream>>>(x, WT1, as1, ad1, Hb1, AS, AD, n);
    node_fused<4, 0><<<ngrid, 256, 0, stream>>>(offsets, csr_src, AS, AD, Hb1, b1, Xb2, n);

    // ---- layer 2 (H=1, mean over 1 head = identity) ----
    gemm_mfma<1, 1><<<ggrid, 256, 0, stream>>>(Xb2, WT2, as2, ad2, Hb2, AS, AD, n);
    node_fused<1, 1><<<ngrid, 256, 0, stream>>>(offsets, csr_src, AS, AD, Hb2, b2, out, n);
}